// Round 6
// baseline (369.280 us; speedup 1.0000x reference)
//
#include <hip/hip_runtime.h>
#include <hip/hip_bf16.h>
#include <cstdint>

// ---------------------------------------------------------------------------
// InteractionMHA, fp32 I/O, bf16-MFMA compute.
// Per branch:
//   Q  = rep_q  @ Wq^T + bq           (gemm_kernel -> BQ bf16)
//   K  = rep_kv @ Wk^T + bk           (gemm_kernel -> BK bf16)
//   Vt = Wv @ rep_kv^T (+bv per row)  (gemm_kernel -> BV bf16, V transposed)
//   out = gelu(softmax(QK^T/16)V @ Wm^T + bm)   (attn_out_kernel, fp32 out)
//
// Round-6 change: out-projection fused INTO the per-graph attention block via
// an LDS transpose (XT reuses the K/P LDS region), eliminating the X ws
// round-trip whose producer->consumer handoff ran at ~900 GB/s effective
// (rounds 4/5: gemm_out 60-74us, MfmaUtil 2.6%). Wm is pre-converted to bf16
// once (cvt_kernel) so out-proj B-frags are direct 16B loads from L2.
// ---------------------------------------------------------------------------

typedef short s16x8 __attribute__((ext_vector_type(8)));
typedef float f32x4 __attribute__((ext_vector_type(4)));

__device__ __forceinline__ float fast_gelu(float x) {
  // exact gelu via A&S 7.1.26 erf (|eps| <= 1.5e-7)
  float ax = fabsf(x);
  float t = 1.0f / (1.0f + 0.3275911f * (ax * 0.70710678f));
  float y = t * (0.254829592f + t * (-0.284496736f + t * (1.421413741f +
            t * (-1.453152027f + t * 1.061405429f))));
  float er = 1.0f - y * __expf(-0.5f * ax * ax);
  er = (x < 0.f) ? -er : er;
  return 0.5f * x * (1.0f + er);
}

__global__ void sentinel_kernel(float* out, float v) {
  if (threadIdx.x == 0 && blockIdx.x == 0) out[0] = v;
}

__global__ void scan_kernel(const int* __restrict__ na, int* __restrict__ offs,
                            int B, int total, float* out) {
  if (threadIdx.x != 0 || blockIdx.x != 0) return;
  long long s = 0;
  for (int b = 0; b < B; ++b) s += na[b];
  if (s == (long long)total) {
    int acc = 0;
    for (int b = 0; b < B; ++b) { offs[b] = acc; acc += na[b]; }
    offs[B] = acc;
    return;
  }
  const long long* na64 = (const long long*)na;
  s = 0;
  for (int b = 0; b < B; ++b) s += na64[b];
  if (s == (long long)total) {
    int acc = 0;
    for (int b = 0; b < B; ++b) { offs[b] = acc; acc += (int)na64[b]; }
    offs[B] = acc;
    return;
  }
  for (int b = 0; b <= B; ++b) offs[b] = 0;
  out[0] = 31337.0f;
}

// fp32 -> bf16 elementwise (Wm weights for the fused out-proj)
__global__ void cvt_kernel(const float* __restrict__ in, __bf16* __restrict__ out, int n) {
  int i = (blockIdx.x * 256 + threadIdx.x) * 4;
  if (i + 3 < n) {
    float4 f = *(const float4*)(in + i);
    out[i + 0] = (__bf16)f.x; out[i + 1] = (__bf16)f.y;
    out[i + 2] = (__bf16)f.z; out[i + 3] = (__bf16)f.w;
  }
}

// ---------- GEMM: C[M][N] = A[M][256] @ Bw[N][256]^T + bias (fp32->bf16) ---
__global__ __launch_bounds__(256) void gemm_kernel(
    const float* __restrict__ A, const float* __restrict__ Bw,
    const float* __restrict__ bias, __bf16* __restrict__ C,
    int N, int biasRow)
{
  __shared__ __bf16 At[128 * 32];
  __shared__ __bf16 Bt[128 * 32];
  const int t = threadIdx.x;
  const int lane = t & 63, w = t >> 6;
  const int wr = w >> 1, wc = w & 1;
  const int l15 = lane & 15, l4 = lane >> 4;
  const int by = blockIdx.x, bx = blockIdx.y;

  f32x4 acc[4][4];
  for (int m = 0; m < 4; ++m)
    for (int nn = 0; nn < 4; ++nn) acc[m][nn] = (f32x4){0.f, 0.f, 0.f, 0.f};

  for (int kk = 0; kk < 256; kk += 32) {
    for (int j = 0; j < 2; ++j) {
      int c = t + j * 256;
      int row = c >> 2, off0 = (c & 3) * 8;
      const float* ap = A + (size_t)(by * 128 + row) * 256 + kk + off0;
      const float* bp = Bw + (size_t)(bx * 128 + row) * 256 + kk + off0;
      float4 a0 = *(const float4*)ap, a1 = *(const float4*)(ap + 4);
      float4 b0 = *(const float4*)bp, b1 = *(const float4*)(bp + 4);
      union { s16x8 v; __bf16 e[8]; } pa, pb;
      pa.e[0] = (__bf16)a0.x; pa.e[1] = (__bf16)a0.y; pa.e[2] = (__bf16)a0.z; pa.e[3] = (__bf16)a0.w;
      pa.e[4] = (__bf16)a1.x; pa.e[5] = (__bf16)a1.y; pa.e[6] = (__bf16)a1.z; pa.e[7] = (__bf16)a1.w;
      pb.e[0] = (__bf16)b0.x; pb.e[1] = (__bf16)b0.y; pb.e[2] = (__bf16)b0.z; pb.e[3] = (__bf16)b0.w;
      pb.e[4] = (__bf16)b1.x; pb.e[5] = (__bf16)b1.y; pb.e[6] = (__bf16)b1.z; pb.e[7] = (__bf16)b1.w;
      *(s16x8*)(&At[row * 32 + off0]) = pa.v;
      *(s16x8*)(&Bt[row * 32 + off0]) = pb.v;
    }
    __syncthreads();
    s16x8 af[4], bfr[4];
    for (int m = 0; m < 4; ++m)
      af[m] = *(const s16x8*)(&At[(wr * 64 + m * 16 + l15) * 32 + l4 * 8]);
    for (int nn = 0; nn < 4; ++nn)
      bfr[nn] = *(const s16x8*)(&Bt[(wc * 64 + nn * 16 + l15) * 32 + l4 * 8]);
    for (int m = 0; m < 4; ++m)
      for (int nn = 0; nn < 4; ++nn)
        acc[m][nn] = __builtin_amdgcn_mfma_f32_16x16x32_bf16(af[m], bfr[nn], acc[m][nn], 0, 0, 0);
    __syncthreads();
  }

  for (int m = 0; m < 4; ++m) {
    int row0 = by * 128 + wr * 64 + m * 16 + l4 * 4;
    for (int nn = 0; nn < 4; ++nn) {
      int col = bx * 128 + wc * 64 + nn * 16 + l15;
      float bc = biasRow ? 0.f : bias[col];
      for (int r = 0; r < 4; ++r) {
        int row = row0 + r;
        float v = acc[m][nn][r] + (biasRow ? bias[row] : bc);
        C[(size_t)row * N + col] = (__bf16)v;
      }
    }
  }
}

// ---------- fused attention + out-proj + GELU (fp32 out) -------------------
// 1 block/graph, 8 waves. Phases (LDS region reused K -> P -> XT):
//  1) stage K in LDS; load Q frags            2) S=QK^T (+V prefetch)
//  3) softmax -> Plds                         4) PV: wave w -> X[all q][w*32+32)
//  5) all waves write X frags -> XT[128][264] (full LDS region)
//  6) out-proj: wave w -> O[q in w*16+16)][all 256], bias+gelu, fp32 store
#define KSTR 264
#define PSTR 136
__global__ __launch_bounds__(512, 4) void attn_out_kernel(
    const __bf16* __restrict__ Q, const __bf16* __restrict__ Km,
    const __bf16* __restrict__ Vt, const __bf16* __restrict__ Wm,
    const float* __restrict__ bm, float* __restrict__ Out,
    const int* __restrict__ offs, int total)
{
  __shared__ __bf16 smem[128 * KSTR];                 // 67.6 KB
  __bf16 (*Klds)[KSTR] = (__bf16(*)[KSTR])smem;
  __bf16 (*Plds)[PSTR] = (__bf16(*)[PSTR])smem;       // alias, after QK
  __bf16 (*XT)[KSTR]   = (__bf16(*)[KSTR])smem;       // alias, after PV

  const int g = blockIdx.x;
  const int off = offs[g];
  const int n = offs[g + 1] - off;
  const int t = threadIdx.x, lane = t & 63, w = t >> 6;
  const int l15 = lane & 15, l4 = lane >> 4;
  const bool qact = (w * 16) < n;

  // ---- phase 1: stage K rows 0..127 (overrun past n reads valid ws, masked)
  uint4 kst[8];
  #pragma unroll
  for (int j = 0; j < 8; ++j) {
    int row = j * 16 + (t >> 5);
    kst[j] = *(const uint4*)((const char*)(Km + (size_t)(off + row) * 256) + (t & 31) * 16);
  }
  s16x8 qf[8];
  if (qact) {
    int qr = w * 16 + l15; if (qr >= n) qr = n - 1;
    const __bf16* qp = Q + (size_t)(off + qr) * 256 + l4 * 8;
    #pragma unroll
    for (int kk = 0; kk < 8; ++kk) qf[kk] = *(const s16x8*)(qp + kk * 32);
  }
  #pragma unroll
  for (int j = 0; j < 8; ++j) {
    int row = j * 16 + (t >> 5);
    *(uint4*)((char*)&Klds[row][0] + (t & 31) * 16) = kst[j];
  }
  __syncthreads();

  // ---- phase 2: S = Q K^T
  f32x4 sacc[8];
  #pragma unroll
  for (int i = 0; i < 8; ++i) sacc[i] = (f32x4){0.f, 0.f, 0.f, 0.f};
  if (qact) {
    #pragma unroll
    for (int kt = 0; kt < 8; ++kt) {
      if (kt * 16 < n) {
        const __bf16* kp = &Klds[kt * 16 + l15][l4 * 8];
        #pragma unroll
        for (int kk = 0; kk < 8; ++kk) {
          s16x8 kf = *(const s16x8*)(kp + kk * 32);
          sacc[kt] = __builtin_amdgcn_mfma_f32_16x16x32_bf16(qf[kk], kf, sacc[kt], 0, 0, 0);
        }
      }
    }
  }
  // V prefetch (retires under softmax); wave w owns d in [w*32, w*32+32)
  const int dbase = w * 32;
  s16x8 vf0[4], vf1[4];
  {
    int d0 = dbase + l15, d1 = dbase + 16 + l15;
    #pragma unroll
    for (int ks = 0; ks < 4; ++ks) {
      int kc = off + ks * 32 + l4 * 8;
      if (kc > total - 8) kc = total - 8;             // P=0 there; finite data
      vf0[ks] = *(const s16x8*)(Vt + (size_t)d0 * total + kc);
      vf1[ks] = *(const s16x8*)(Vt + (size_t)d1 * total + kc);
    }
  }
  __syncthreads();                                    // Klds reads complete

  // ---- phase 3: softmax (regs) -> Plds bf16
  if (qact) {
    #pragma unroll
    for (int r = 0; r < 4; ++r) {
      float sv[8];
      float m = -1e30f;
      #pragma unroll
      for (int kt = 0; kt < 8; ++kt) {
        int key = kt * 16 + l15;
        float v = (key < n) ? sacc[kt][r] * 0.0625f : -1e30f;
        sv[kt] = v; m = fmaxf(m, v);
      }
      for (int o = 1; o < 16; o <<= 1) m = fmaxf(m, __shfl_xor(m, o));
      float p[8], sum = 0.f;
      #pragma unroll
      for (int kt = 0; kt < 8; ++kt) { p[kt] = __expf(sv[kt] - m); sum += p[kt]; }
      for (int o = 1; o < 16; o <<= 1) sum += __shfl_xor(sum, o);
      float inv = 1.f / sum;
      int q = w * 16 + l4 * 4 + r;
      #pragma unroll
      for (int kt = 0; kt < 8; ++kt)
        Plds[q][kt * 16 + l15] = (__bf16)(p[kt] * inv);   // masked keys -> 0
    }
  }
  __syncthreads();                                    // Plds complete

  // ---- phase 4: PV -> xacc (wave w: all 128 q, d in [dbase, dbase+32))
  f32x4 xacc[2][8];
  #pragma unroll
  for (int dt = 0; dt < 2; ++dt)
    #pragma unroll
    for (int qm = 0; qm < 8; ++qm) xacc[dt][qm] = (f32x4){0.f, 0.f, 0.f, 0.f};
  #pragma unroll
  for (int qm = 0; qm < 8; ++qm) {
    #pragma unroll
    for (int ks = 0; ks < 4; ++ks) {
      if (ks * 32 < n) {
        s16x8 pa = *(const s16x8*)(&Plds[qm * 16 + l15][ks * 32 + l4 * 8]);
        xacc[0][qm] = __builtin_amdgcn_mfma_f32_16x16x32_bf16(pa, vf0[ks], xacc[0][qm], 0, 0, 0);
        xacc[1][qm] = __builtin_amdgcn_mfma_f32_16x16x32_bf16(pa, vf1[ks], xacc[1][qm], 0, 0, 0);
      }
    }
  }
  __syncthreads();                                    // Plds reads done

  // ---- phase 5: X frags -> XT[q][d] (full region; 2-way-free banks)
  #pragma unroll
  for (int dt = 0; dt < 2; ++dt)
    #pragma unroll
    for (int qm = 0; qm < 8; ++qm)
      #pragma unroll
      for (int r = 0; r < 4; ++r)
        XT[qm * 16 + l4 * 4 + r][dbase + dt * 16 + l15] = (__bf16)xacc[dt][qm][r];
  __syncthreads();                                    // XT complete

  // ---- phase 6: O[16 q][256] = X @ Wm^T; A from XT, B from bf16 Wm (L2)
  f32x4 oacc[16];
  #pragma unroll
  for (int i = 0; i < 16; ++i) oacc[i] = (f32x4){0.f, 0.f, 0.f, 0.f};
  #pragma unroll
  for (int ks = 0; ks < 8; ++ks) {
    s16x8 af = *(const s16x8*)(&XT[w * 16 + l15][ks * 32 + l4 * 8]);
    const __bf16* wp = Wm + (size_t)l15 * 256 + ks * 32 + l4 * 8;
    #pragma unroll
    for (int jt = 0; jt < 16; ++jt) {
      s16x8 bfr = *(const s16x8*)(wp + (size_t)jt * 16 * 256);
      oacc[jt] = __builtin_amdgcn_mfma_f32_16x16x32_bf16(af, bfr, oacc[jt], 0, 0, 0);
    }
  }

  // epilogue: +bias, gelu, fp32 store (rows q<n)
  #pragma unroll
  for (int jt = 0; jt < 16; ++jt) {
    int col = jt * 16 + l15;
    float bb = bm[col];
    #pragma unroll
    for (int r = 0; r < 4; ++r) {
      int q = w * 16 + l4 * 4 + r;
      if (q < n) {
        float v = fast_gelu(oacc[jt][r] + bb);
        Out[(size_t)(off + q) * 256 + col] = v;
      }
    }
  }
}

// ---------------------------------------------------------------------------
extern "C" void kernel_launch(void* const* d_in, const int* in_sizes, int n_in,
                              void* d_out, int out_size, void* d_ws, size_t ws_size,
                              hipStream_t stream) {
  const float* rep2d = (const float*)d_in[0];
  const float* rep3d = (const float*)d_in[1];
  const int*   na    = (const int*)d_in[2];
  const float* wq23 = (const float*)d_in[3];  const float* bq23 = (const float*)d_in[4];
  const float* wk23 = (const float*)d_in[5];  const float* bk23 = (const float*)d_in[6];
  const float* wv23 = (const float*)d_in[7];  const float* bv23 = (const float*)d_in[8];
  const float* wq32 = (const float*)d_in[9];  const float* bq32 = (const float*)d_in[10];
  const float* wk32 = (const float*)d_in[11]; const float* bk32 = (const float*)d_in[12];
  const float* wv32 = (const float*)d_in[13]; const float* bv32 = (const float*)d_in[14];
  const float* wm23 = (const float*)d_in[15]; const float* bm23 = (const float*)d_in[16];
  const float* wm32 = (const float*)d_in[17]; const float* bm32 = (const float*)d_in[18];

  const int B = in_sizes[2];
  const int total = in_sizes[0] / 256;           // 40960
  float* out = (float*)d_out;

  char* ws = (char*)d_ws;
  const size_t SZ = (size_t)total * 256 * sizeof(__bf16);  // 20.97 MB
  const size_t WMB = 65536 * sizeof(__bf16);               // 128 KB each
  const size_t need = 8192 + 2 * WMB + 3 * SZ;             // 63.2 MB (proven ok)
  if (ws_size < need) {
    sentinel_kernel<<<1, 64, 0, stream>>>(out, 54321.0f);
    return;
  }
  int*    offs = (int*)ws;
  __bf16* WM0 = (__bf16*)(ws + 8192);
  __bf16* WM1 = (__bf16*)(ws + 8192 + WMB);
  __bf16* BQ  = (__bf16*)(ws + 8192 + 2 * WMB);
  __bf16* BK  = (__bf16*)(ws + 8192 + 2 * WMB + SZ);
  __bf16* BV  = (__bf16*)(ws + 8192 + 2 * WMB + 2 * SZ);   // V transposed

  scan_kernel<<<1, 64, 0, stream>>>(na, offs, B, total, out);
  cvt_kernel<<<64, 256, 0, stream>>>(wm23, WM0, 65536);
  cvt_kernel<<<64, 256, 0, stream>>>(wm32, WM1, 65536);

  dim3 blk(256);
  dim3 gP(total / 128, 2);   // [total,256] gemms
  dim3 gV(2, total / 128);   // transposed-V gemm: M=256, N=total
  dim3 gA(B);                // fused attention+outproj: 1 block/graph
  dim3 blkA(512);

  // branch 2d -> 3d
  gemm_kernel<<<gP, blk, 0, stream>>>(rep2d, wq23, bq23, BQ, 256, 0);
  gemm_kernel<<<gP, blk, 0, stream>>>(rep3d, wk23, bk23, BK, 256, 0);
  gemm_kernel<<<gV, blk, 0, stream>>>(wv23, rep3d, bv23, BV, total, 1);
  attn_out_kernel<<<gA, blkA, 0, stream>>>(BQ, BK, BV, WM0, bm23, out, offs, total);

  // branch 3d -> 2d
  gemm_kernel<<<gP, blk, 0, stream>>>(rep3d, wq32, bq32, BQ, 256, 0);
  gemm_kernel<<<gP, blk, 0, stream>>>(rep2d, wk32, bk32, BK, 256, 0);
  gemm_kernel<<<gV, blk, 0, stream>>>(wv32, rep2d, bv32, BV, total, 1);
  attn_out_kernel<<<gA, blkA, 0, stream>>>(BQ, BK, BV, WM1, bm32,
                                           out + (size_t)total * 256, offs, total);
}

// Round 7
// 277.294 us; speedup vs baseline: 1.3317x; 1.3317x over previous
//
#include <hip/hip_runtime.h>
#include <hip/hip_bf16.h>
#include <cstdint>

// ---------------------------------------------------------------------------
// InteractionMHA, fp32 I/O, bf16-MFMA compute.
// Per branch:
//   Q  = rep_q  @ Wq^T + bq           (gemm_kernel -> BQ bf16)
//   K  = rep_kv @ Wk^T + bk           (gemm_kernel -> BK bf16)
//   Vt = Wv @ rep_kv^T (+bv per row)  (gemm_kernel -> BV bf16, V transposed)
//   X  = softmax(Q K^T/16) V          (attn_kernel, X -> BQ in-place)
//   out = gelu(X @ Wm^T + bm)         (gemm_out 64-row tiles, fp32 out)
//
// Round-7: gemm_out re-tiled 128x128 -> 64x128 (1280 blocks, ~7 blocks/CU).
// Rounds 4-6 showed all slow dispatches share Occupancy<=25% + nothing busy
// (latency-bound, too little TLP); this attacks that with block count, not
// pipelining (round-5 prefetch + NT stores both regressed and are reverted).
// ---------------------------------------------------------------------------

typedef short s16x8 __attribute__((ext_vector_type(8)));
typedef float f32x4 __attribute__((ext_vector_type(4)));

__device__ __forceinline__ float fast_gelu(float x) {
  // exact gelu via A&S 7.1.26 erf (|eps| <= 1.5e-7)
  float ax = fabsf(x);
  float t = 1.0f / (1.0f + 0.3275911f * (ax * 0.70710678f));
  float y = t * (0.254829592f + t * (-0.284496736f + t * (1.421413741f +
            t * (-1.453152027f + t * 1.061405429f))));
  float er = 1.0f - y * __expf(-0.5f * ax * ax);
  er = (x < 0.f) ? -er : er;
  return 0.5f * x * (1.0f + er);
}

__global__ void sentinel_kernel(float* out, float v) {
  if (threadIdx.x == 0 && blockIdx.x == 0) out[0] = v;
}

__global__ void scan_kernel(const int* __restrict__ na, int* __restrict__ offs,
                            int B, int total, float* out) {
  if (threadIdx.x != 0 || blockIdx.x != 0) return;
  long long s = 0;
  for (int b = 0; b < B; ++b) s += na[b];
  if (s == (long long)total) {
    int acc = 0;
    for (int b = 0; b < B; ++b) { offs[b] = acc; acc += na[b]; }
    offs[B] = acc;
    return;
  }
  const long long* na64 = (const long long*)na;
  s = 0;
  for (int b = 0; b < B; ++b) s += na64[b];
  if (s == (long long)total) {
    int acc = 0;
    for (int b = 0; b < B; ++b) { offs[b] = acc; acc += (int)na64[b]; }
    offs[B] = acc;
    return;
  }
  for (int b = 0; b <= B; ++b) offs[b] = 0;
  out[0] = 31337.0f;
}

// ---------- GEMM: C[M][N] = A[M][256] @ Bw[N][256]^T + bias (fp32->bf16) ---
__global__ __launch_bounds__(256) void gemm_kernel(
    const float* __restrict__ A, const float* __restrict__ Bw,
    const float* __restrict__ bias, __bf16* __restrict__ C,
    int N, int biasRow)
{
  __shared__ __bf16 At[128 * 32];
  __shared__ __bf16 Bt[128 * 32];
  const int t = threadIdx.x;
  const int lane = t & 63, w = t >> 6;
  const int wr = w >> 1, wc = w & 1;
  const int l15 = lane & 15, l4 = lane >> 4;
  const int by = blockIdx.x, bx = blockIdx.y;

  f32x4 acc[4][4];
  for (int m = 0; m < 4; ++m)
    for (int nn = 0; nn < 4; ++nn) acc[m][nn] = (f32x4){0.f, 0.f, 0.f, 0.f};

  for (int kk = 0; kk < 256; kk += 32) {
    for (int j = 0; j < 2; ++j) {
      int c = t + j * 256;
      int row = c >> 2, off0 = (c & 3) * 8;
      const float* ap = A + (size_t)(by * 128 + row) * 256 + kk + off0;
      const float* bp = Bw + (size_t)(bx * 128 + row) * 256 + kk + off0;
      float4 a0 = *(const float4*)ap, a1 = *(const float4*)(ap + 4);
      float4 b0 = *(const float4*)bp, b1 = *(const float4*)(bp + 4);
      union { s16x8 v; __bf16 e[8]; } pa, pb;
      pa.e[0] = (__bf16)a0.x; pa.e[1] = (__bf16)a0.y; pa.e[2] = (__bf16)a0.z; pa.e[3] = (__bf16)a0.w;
      pa.e[4] = (__bf16)a1.x; pa.e[5] = (__bf16)a1.y; pa.e[6] = (__bf16)a1.z; pa.e[7] = (__bf16)a1.w;
      pb.e[0] = (__bf16)b0.x; pb.e[1] = (__bf16)b0.y; pb.e[2] = (__bf16)b0.z; pb.e[3] = (__bf16)b0.w;
      pb.e[4] = (__bf16)b1.x; pb.e[5] = (__bf16)b1.y; pb.e[6] = (__bf16)b1.z; pb.e[7] = (__bf16)b1.w;
      *(s16x8*)(&At[row * 32 + off0]) = pa.v;
      *(s16x8*)(&Bt[row * 32 + off0]) = pb.v;
    }
    __syncthreads();
    s16x8 af[4], bfr[4];
    for (int m = 0; m < 4; ++m)
      af[m] = *(const s16x8*)(&At[(wr * 64 + m * 16 + l15) * 32 + l4 * 8]);
    for (int nn = 0; nn < 4; ++nn)
      bfr[nn] = *(const s16x8*)(&Bt[(wc * 64 + nn * 16 + l15) * 32 + l4 * 8]);
    for (int m = 0; m < 4; ++m)
      for (int nn = 0; nn < 4; ++nn)
        acc[m][nn] = __builtin_amdgcn_mfma_f32_16x16x32_bf16(af[m], bfr[nn], acc[m][nn], 0, 0, 0);
    __syncthreads();
  }

  for (int m = 0; m < 4; ++m) {
    int row0 = by * 128 + wr * 64 + m * 16 + l4 * 4;
    for (int nn = 0; nn < 4; ++nn) {
      int col = bx * 128 + wc * 64 + nn * 16 + l15;
      float bc = biasRow ? 0.f : bias[col];
      for (int r = 0; r < 4; ++r) {
        int row = row0 + r;
        float v = acc[m][nn][r] + (biasRow ? bias[row] : bc);
        C[(size_t)row * N + col] = (__bf16)v;
      }
    }
  }
}

// ---------- out-proj: out = gelu(X[M][256] @ Wm[256][256]^T + bm), fp32 ----
// 64x128 tile, BK=32, 4 waves (2x2), wave tile 32x64 = 2x4 frags.
// Small tiles -> 1280 blocks (~7/CU resident) to hide load latency via TLP.
__global__ __launch_bounds__(256) void gemm_out(
    const __bf16* __restrict__ A, const float* __restrict__ Bw,
    const float* __restrict__ bias, float* __restrict__ C, int N)
{
  __shared__ __bf16 At[64 * 32];
  __shared__ __bf16 Bt[128 * 32];
  const int t = threadIdx.x;
  const int lane = t & 63, w = t >> 6;
  const int wr = w >> 1, wc = w & 1;
  const int l15 = lane & 15, l4 = lane >> 4;
  const int by = blockIdx.x, bx = blockIdx.y;

  f32x4 acc[2][4];
  for (int m = 0; m < 2; ++m)
    for (int nn = 0; nn < 4; ++nn) acc[m][nn] = (f32x4){0.f, 0.f, 0.f, 0.f};

  for (int kk = 0; kk < 256; kk += 32) {
    // A: 64x32 bf16 = 256 16B chunks, 1/thread
    {
      int row = t >> 2, off0 = (t & 3) * 8;
      *(s16x8*)(&At[row * 32 + off0]) =
          *(const s16x8*)(A + (size_t)(by * 64 + row) * 256 + kk + off0);
    }
    // B: 128x32 fp32 -> bf16 = 512 8-elem chunks, 2/thread
    for (int j = 0; j < 2; ++j) {
      int c = t + j * 256;
      int row = c >> 2, off0 = (c & 3) * 8;
      const float* bp = Bw + (size_t)(bx * 128 + row) * 256 + kk + off0;
      float4 b0 = *(const float4*)bp, b1 = *(const float4*)(bp + 4);
      union { s16x8 v; __bf16 e[8]; } pb;
      pb.e[0] = (__bf16)b0.x; pb.e[1] = (__bf16)b0.y; pb.e[2] = (__bf16)b0.z; pb.e[3] = (__bf16)b0.w;
      pb.e[4] = (__bf16)b1.x; pb.e[5] = (__bf16)b1.y; pb.e[6] = (__bf16)b1.z; pb.e[7] = (__bf16)b1.w;
      *(s16x8*)(&Bt[row * 32 + off0]) = pb.v;
    }
    __syncthreads();
    s16x8 af[2], bfr[4];
    for (int m = 0; m < 2; ++m)
      af[m] = *(const s16x8*)(&At[(wr * 32 + m * 16 + l15) * 32 + l4 * 8]);
    for (int nn = 0; nn < 4; ++nn)
      bfr[nn] = *(const s16x8*)(&Bt[(wc * 64 + nn * 16 + l15) * 32 + l4 * 8]);
    for (int m = 0; m < 2; ++m)
      for (int nn = 0; nn < 4; ++nn)
        acc[m][nn] = __builtin_amdgcn_mfma_f32_16x16x32_bf16(af[m], bfr[nn], acc[m][nn], 0, 0, 0);
    __syncthreads();
  }

  for (int m = 0; m < 2; ++m) {
    int row0 = by * 64 + wr * 32 + m * 16 + l4 * 4;
    for (int nn = 0; nn < 4; ++nn) {
      int col = bx * 128 + wc * 64 + nn * 16 + l15;
      float bc = bias[col];
      for (int r = 0; r < 4; ++r) {
        int row = row0 + r;
        float v = fast_gelu(acc[m][nn][r] + bc);
        C[(size_t)row * N + col] = v;
      }
    }
  }
}

// ---------- attention: X = softmax(Q K^T / 16, key-masked) V --------------
// 1 block/graph, 8 waves. Klds staged once; Plds reuses the same LDS after a
// barrier. Wave w: QK^T+softmax for q rows [w*16,+16); PV for d cols
// [w*32,+32) over ALL q rows (V read once per graph). (round-4 proven 40us)
#define KSTR 264
#define PSTR 136
__global__ __launch_bounds__(512, 2) void attn_kernel(
    const __bf16* __restrict__ Q, const __bf16* __restrict__ Km,
    const __bf16* __restrict__ Vt, __bf16* __restrict__ X,
    const int* __restrict__ offs, int total)
{
  __shared__ __bf16 smem[128 * KSTR];                 // 67.6 KB, K then P
  __bf16 (*Klds)[KSTR] = (__bf16(*)[KSTR])smem;
  __bf16 (*Plds)[PSTR] = (__bf16(*)[PSTR])smem;

  const int g = blockIdx.x;
  const int off = offs[g];
  const int n = offs[g + 1] - off;
  const int t = threadIdx.x, lane = t & 63, w = t >> 6;
  const int l15 = lane & 15, l4 = lane >> 4;
  const bool qact = (w * 16) < n;

  // ---- stage K rows 0..127 (overrun beyond n reads valid ws, masked later)
  uint4 kst[8];
  #pragma unroll
  for (int j = 0; j < 8; ++j) {
    int row = j * 16 + (t >> 5);
    kst[j] = *(const uint4*)((const char*)(Km + (size_t)(off + row) * 256) + (t & 31) * 16);
  }
  // ---- Q frags for this wave's 16 rows
  s16x8 qf[8];
  if (qact) {
    int qr = w * 16 + l15; if (qr >= n) qr = n - 1;
    const __bf16* qp = Q + (size_t)(off + qr) * 256 + l4 * 8;
    #pragma unroll
    for (int kk = 0; kk < 8; ++kk) qf[kk] = *(const s16x8*)(qp + kk * 32);
  }
  #pragma unroll
  for (int j = 0; j < 8; ++j) {
    int row = j * 16 + (t >> 5);
    *(uint4*)((char*)&Klds[row][0] + (t & 31) * 16) = kst[j];
  }
  __syncthreads();

  // ---- S = Q K^T (from Klds)
  f32x4 sacc[8];
  #pragma unroll
  for (int i = 0; i < 8; ++i) sacc[i] = (f32x4){0.f, 0.f, 0.f, 0.f};
  if (qact) {
    #pragma unroll
    for (int kt = 0; kt < 8; ++kt) {
      if (kt * 16 < n) {
        const __bf16* kp = &Klds[kt * 16 + l15][l4 * 8];
        #pragma unroll
        for (int kk = 0; kk < 8; ++kk) {
          s16x8 kf = *(const s16x8*)(kp + kk * 32);
          sacc[kt] = __builtin_amdgcn_mfma_f32_16x16x32_bf16(qf[kk], kf, sacc[kt], 0, 0, 0);
        }
      }
    }
  }
  __syncthreads();                                    // Klds reads complete

  // ---- softmax (registers) -> Plds (bf16)
  if (qact) {
    #pragma unroll
    for (int r = 0; r < 4; ++r) {
      float sv[8];
      float m = -1e30f;
      #pragma unroll
      for (int kt = 0; kt < 8; ++kt) {
        int key = kt * 16 + l15;
        float v = (key < n) ? sacc[kt][r] * 0.0625f : -1e30f;
        sv[kt] = v; m = fmaxf(m, v);
      }
      for (int o = 1; o < 16; o <<= 1) m = fmaxf(m, __shfl_xor(m, o));
      float p[8], sum = 0.f;
      #pragma unroll
      for (int kt = 0; kt < 8; ++kt) { p[kt] = __expf(sv[kt] - m); sum += p[kt]; }
      for (int o = 1; o < 16; o <<= 1) sum += __shfl_xor(sum, o);
      float inv = 1.f / sum;
      int q = w * 16 + l4 * 4 + r;
      #pragma unroll
      for (int kt = 0; kt < 8; ++kt)
        Plds[q][kt * 16 + l15] = (__bf16)(p[kt] * inv);   // masked keys -> 0
    }
  }
  __syncthreads();                                    // Plds complete

  // ---- PV: wave w computes X[all 128 q][d in w*32..w*32+32)
  const int dbase = w * 32;
  f32x4 xacc[2][8];
  #pragma unroll
  for (int dt = 0; dt < 2; ++dt)
    #pragma unroll
    for (int qm = 0; qm < 8; ++qm) xacc[dt][qm] = (f32x4){0.f, 0.f, 0.f, 0.f};

  #pragma unroll
  for (int dt = 0; dt < 2; ++dt) {
    int d = dbase + dt * 16 + l15;
    s16x8 vf[4];
    #pragma unroll
    for (int ks = 0; ks < 4; ++ks) {
      int kc = off + ks * 32 + l4 * 8;
      if (kc > total - 8) kc = total - 8;             // P=0 there; data finite
      vf[ks] = *(const s16x8*)(Vt + (size_t)d * total + kc);
    }
    #pragma unroll
    for (int qm = 0; qm < 8; ++qm) {
      #pragma unroll
      for (int ks = 0; ks < 4; ++ks) {
        if (ks * 32 < n) {
          s16x8 pa = *(const s16x8*)(&Plds[qm * 16 + l15][ks * 32 + l4 * 8]);
          xacc[dt][qm] = __builtin_amdgcn_mfma_f32_16x16x32_bf16(pa, vf[ks], xacc[dt][qm], 0, 0, 0);
        }
      }
    }
  }

  // ---- store X (bf16) rows q<n
  #pragma unroll
  for (int dt = 0; dt < 2; ++dt)
    #pragma unroll
    for (int qm = 0; qm < 8; ++qm)
      #pragma unroll
      for (int r = 0; r < 4; ++r) {
        int q = qm * 16 + l4 * 4 + r;
        if (q < n)
          X[(size_t)(off + q) * 256 + dbase + dt * 16 + l15] = (__bf16)xacc[dt][qm][r];
      }
}

// ---------------------------------------------------------------------------
extern "C" void kernel_launch(void* const* d_in, const int* in_sizes, int n_in,
                              void* d_out, int out_size, void* d_ws, size_t ws_size,
                              hipStream_t stream) {
  const float* rep2d = (const float*)d_in[0];
  const float* rep3d = (const float*)d_in[1];
  const int*   na    = (const int*)d_in[2];
  const float* wq23 = (const float*)d_in[3];  const float* bq23 = (const float*)d_in[4];
  const float* wk23 = (const float*)d_in[5];  const float* bk23 = (const float*)d_in[6];
  const float* wv23 = (const float*)d_in[7];  const float* bv23 = (const float*)d_in[8];
  const float* wq32 = (const float*)d_in[9];  const float* bq32 = (const float*)d_in[10];
  const float* wk32 = (const float*)d_in[11]; const float* bk32 = (const float*)d_in[12];
  const float* wv32 = (const float*)d_in[13]; const float* bv32 = (const float*)d_in[14];
  const float* wm23 = (const float*)d_in[15]; const float* bm23 = (const float*)d_in[16];
  const float* wm32 = (const float*)d_in[17]; const float* bm32 = (const float*)d_in[18];

  const int B = in_sizes[2];
  const int total = in_sizes[0] / 256;           // 40960
  float* out = (float*)d_out;

  char* ws = (char*)d_ws;
  const size_t SZ = (size_t)total * 256 * sizeof(__bf16);  // 20.97 MB
  const size_t need = 8192 + 3 * SZ;                       // 62.9 MB (proven ok)
  if (ws_size < need) {
    sentinel_kernel<<<1, 64, 0, stream>>>(out, 54321.0f);
    return;
  }
  int*    offs = (int*)ws;
  __bf16* BQ = (__bf16*)(ws + 8192);             // Q, then X in-place
  __bf16* BK = (__bf16*)(ws + 8192 + SZ);
  __bf16* BV = (__bf16*)(ws + 8192 + 2 * SZ);    // transposed V [256][total]

  scan_kernel<<<1, 64, 0, stream>>>(na, offs, B, total, out);

  dim3 blk(256);
  dim3 gP(total / 128, 2);   // [total,256] gemms
  dim3 gV(2, total / 128);   // transposed-V gemm: M=256, N=total
  dim3 gO(total / 64, 2);    // out-proj, 64-row tiles (1280 blocks)
  dim3 gA(B);                // attention: 1 block/graph
  dim3 blkA(512);

  // branch 2d -> 3d
  gemm_kernel<<<gP, blk, 0, stream>>>(rep2d, wq23, bq23, BQ, 256, 0);
  gemm_kernel<<<gP, blk, 0, stream>>>(rep3d, wk23, bk23, BK, 256, 0);
  gemm_kernel<<<gV, blk, 0, stream>>>(wv23, rep3d, bv23, BV, total, 1);
  attn_kernel<<<gA, blkA, 0, stream>>>(BQ, BK, BV, BQ, offs, total);
  gemm_out<<<gO, blk, 0, stream>>>(BQ, wm23, bm23, out, 256);

  // branch 3d -> 2d
  gemm_kernel<<<gP, blk, 0, stream>>>(rep3d, wq32, bq32, BQ, 256, 0);
  gemm_kernel<<<gP, blk, 0, stream>>>(rep2d, wk32, bk32, BK, 256, 0);
  gemm_kernel<<<gV, blk, 0, stream>>>(wv32, rep2d, bv32, BV, total, 1);
  attn_kernel<<<gA, blkA, 0, stream>>>(BQ, BK, BV, BQ, offs, total);
  gemm_out<<<gO, blk, 0, stream>>>(BQ, wm32, bm32, out + (size_t)total * 256, 256);
}

// Round 8
// 215.992 us; speedup vs baseline: 1.7097x; 1.2838x over previous
//
#include <hip/hip_runtime.h>
#include <hip/hip_bf16.h>
#include <cstdint>

// ---------------------------------------------------------------------------
// InteractionMHA, fp32 I/O, bf16-MFMA compute.
// Fused-QKV path (ws >= 126MB): per SOURCE tensor one kernel computes the 3
// projections (A staged once in LDS; V stored transposed from C-frags):
//   qkv_fused(rep2d): Q23->BQ1, K32->BK2, V32->BV2
//   qkv_fused(rep3d): Q32->BQ2, K23->BK1, V23->BV1
//   attn(BQ1,BK1,BV1)->BQ1 ; gelu-proj(BQ1,Wm23)->out[0:half]
//   attn(BQ2,BK2,BV2)->BQ2 ; gelu-proj(BQ2,Wm32)->out[half:]
// Fallback path (ws >= 63MB): round-7 separate gemms, 3 buffers.
// Round-8 fixes: scan_kernel was 53us (single-thread serial loop, top
// dispatch in round-7 profile) -> parallel LDS scan ~3us. QKV fusion removes
// 2 of 3 HBM re-reads of each rep tensor (378MB -> 210MB).
// ---------------------------------------------------------------------------

typedef short s16x8 __attribute__((ext_vector_type(8)));
typedef float f32x4 __attribute__((ext_vector_type(4)));

__device__ __forceinline__ s16x8 cvt8(const float* p) {
  float4 a0 = *(const float4*)p, a1 = *(const float4*)(p + 4);
  union { s16x8 v; __bf16 e[8]; } u;
  u.e[0] = (__bf16)a0.x; u.e[1] = (__bf16)a0.y; u.e[2] = (__bf16)a0.z; u.e[3] = (__bf16)a0.w;
  u.e[4] = (__bf16)a1.x; u.e[5] = (__bf16)a1.y; u.e[6] = (__bf16)a1.z; u.e[7] = (__bf16)a1.w;
  return u.v;
}
__device__ __forceinline__ float fast_gelu(float x) {
  float ax = fabsf(x);
  float t = 1.0f / (1.0f + 0.3275911f * (ax * 0.70710678f));
  float y = t * (0.254829592f + t * (-0.284496736f + t * (1.421413741f +
            t * (-1.453152027f + t * 1.061405429f))));
  float er = 1.0f - y * __expf(-0.5f * ax * ax);
  er = (x < 0.f) ? -er : er;
  return 0.5f * x * (1.0f + er);
}

__global__ void sentinel_kernel(float* out, float v) {
  if (threadIdx.x == 0 && blockIdx.x == 0) out[0] = v;
}

// ---------- parallel offsets scan (B <= 512), dtype self-validating --------
__global__ __launch_bounds__(512) void scan_kernel(
    const int* __restrict__ na, int* __restrict__ offs,
    int B, int total, float* out)
{
  __shared__ int s32[512];
  __shared__ int s64[512];
  const int t = threadIdx.x;
  int v32 = 0, v64 = 0;
  if (t < B) {
    v32 = na[t];
    v64 = (int)((const long long*)na)[t];
  }
  s32[t] = v32; s64[t] = v64;
  __syncthreads();
  for (int o = 1; o < 512; o <<= 1) {
    int a = (t >= o) ? s32[t - o] : 0;
    int b = (t >= o) ? s64[t - o] : 0;
    __syncthreads();
    s32[t] += a; s64[t] += b;
    __syncthreads();
  }
  int tot32 = s32[B - 1], tot64 = s64[B - 1];
  bool ok32 = (tot32 == total), ok64 = (tot64 == total);
  if (t < B) offs[t] = ok32 ? (s32[t] - v32) : ok64 ? (s64[t] - v64) : 0;
  if (t == 0) {
    offs[B] = ok32 ? tot32 : ok64 ? tot64 : 0;
    if (!ok32 && !ok64) out[0] = 31337.0f;
  }
}

// ---------- fused QKV: 3 projections from one source, A staged once -------
// block = 64 rows x 256 thr (4 waves 2x2, wave tile 32x64); 6 passes
// (3 weights x 2 col-halves); V output stored TRANSPOSED [256][total].
__global__ __launch_bounds__(256) void qkv_fused(
    const float* __restrict__ A,
    const float* __restrict__ Wq, const float* __restrict__ bq,
    const float* __restrict__ Wk, const float* __restrict__ bk,
    const float* __restrict__ Wv, const float* __restrict__ bv,
    __bf16* __restrict__ Qo, __bf16* __restrict__ Ko, __bf16* __restrict__ Vt,
    int total)
{
  __shared__ __bf16 Al[64][264];        // 33.8 KB, pad-264 (2-way banks)
  __shared__ __bf16 Wt[128][40];        // 10.2 KB
  const int t = threadIdx.x, lane = t & 63, w = t >> 6;
  const int wr = w >> 1, wc = w & 1;
  const int l15 = lane & 15, l4 = lane >> 4;
  const int by = blockIdx.x;

  // stage A rows [by*64, +64) fp32->bf16 (read once for all 3 outputs)
  #pragma unroll
  for (int j = 0; j < 8; ++j) {
    int c = t + j * 256;                 // 2048 chunks of 8 elems
    int row = c >> 5, off0 = (c & 31) * 8;
    *(s16x8*)(&Al[row][off0]) = cvt8(A + (size_t)(by * 64 + row) * 256 + off0);
  }
  __syncthreads();

  #pragma unroll
  for (int wi = 0; wi < 3; ++wi) {
    const float* W  = (wi == 0) ? Wq : (wi == 1) ? Wk : Wv;
    const float* bs = (wi == 0) ? bq : (wi == 1) ? bk : bv;
    #pragma unroll
    for (int nx = 0; nx < 2; ++nx) {
      f32x4 acc[2][4];
      #pragma unroll
      for (int m = 0; m < 2; ++m)
        #pragma unroll
        for (int nn = 0; nn < 4; ++nn) acc[m][nn] = (f32x4){0.f, 0.f, 0.f, 0.f};

      for (int kk = 0; kk < 256; kk += 32) {
        __syncthreads();                 // Wt readers (prev iter/pass) done
        #pragma unroll
        for (int j = 0; j < 2; ++j) {
          int c = t + j * 256;
          int row = c >> 2, off0 = (c & 3) * 8;
          *(s16x8*)(&Wt[row][off0]) =
              cvt8(W + (size_t)(nx * 128 + row) * 256 + kk + off0);
        }
        __syncthreads();
        s16x8 af[2], bfr[4];
        #pragma unroll
        for (int m = 0; m < 2; ++m)
          af[m] = *(const s16x8*)(&Al[wr * 32 + m * 16 + l15][kk + l4 * 8]);
        #pragma unroll
        for (int nn = 0; nn < 4; ++nn)
          bfr[nn] = *(const s16x8*)(&Wt[wc * 64 + nn * 16 + l15][l4 * 8]);
        #pragma unroll
        for (int m = 0; m < 2; ++m)
          #pragma unroll
          for (int nn = 0; nn < 4; ++nn)
            acc[m][nn] = __builtin_amdgcn_mfma_f32_16x16x32_bf16(af[m], bfr[nn], acc[m][nn], 0, 0, 0);
      }

      if (wi < 2) {                      // Q or K: row-major store
        __bf16* O = (wi == 0) ? Qo : Ko;
        #pragma unroll
        for (int m = 0; m < 2; ++m) {
          int row0 = by * 64 + wr * 32 + m * 16 + l4 * 4;
          #pragma unroll
          for (int nn = 0; nn < 4; ++nn) {
            int col = nx * 128 + wc * 64 + nn * 16 + l15;
            float bc = bs[col];
            #pragma unroll
            for (int r = 0; r < 4; ++r)
              O[(size_t)(row0 + r) * 256 + col] = (__bf16)(acc[m][nn][r] + bc);
          }
        }
      } else {                           // V: transposed store, 8B packs
        #pragma unroll
        for (int m = 0; m < 2; ++m) {
          int row0 = by * 64 + wr * 32 + m * 16 + l4 * 4;
          #pragma unroll
          for (int nn = 0; nn < 4; ++nn) {
            int col = nx * 128 + wc * 64 + nn * 16 + l15;
            float bc = bs[col];
            union { uint2 u; __bf16 e[4]; } pv;
            #pragma unroll
            for (int r = 0; r < 4; ++r) pv.e[r] = (__bf16)(acc[m][nn][r] + bc);
            *(uint2*)(&Vt[(size_t)col * total + row0]) = pv.u;
          }
        }
      }
    }
  }
}

// ---------- fallback GEMM (round-7): C = A@Bw^T + bias, fp32->bf16 --------
__global__ __launch_bounds__(256) void gemm_kernel(
    const float* __restrict__ A, const float* __restrict__ Bw,
    const float* __restrict__ bias, __bf16* __restrict__ C,
    int N, int biasRow)
{
  __shared__ __bf16 At[128 * 32];
  __shared__ __bf16 Bt[128 * 32];
  const int t = threadIdx.x;
  const int lane = t & 63, w = t >> 6;
  const int wr = w >> 1, wc = w & 1;
  const int l15 = lane & 15, l4 = lane >> 4;
  const int by = blockIdx.x, bx = blockIdx.y;

  f32x4 acc[4][4];
  for (int m = 0; m < 4; ++m)
    for (int nn = 0; nn < 4; ++nn) acc[m][nn] = (f32x4){0.f, 0.f, 0.f, 0.f};

  for (int kk = 0; kk < 256; kk += 32) {
    for (int j = 0; j < 2; ++j) {
      int c = t + j * 256;
      int row = c >> 2, off0 = (c & 3) * 8;
      *(s16x8*)(&At[row * 32 + off0]) = cvt8(A + (size_t)(by * 128 + row) * 256 + kk + off0);
      *(s16x8*)(&Bt[row * 32 + off0]) = cvt8(Bw + (size_t)(bx * 128 + row) * 256 + kk + off0);
    }
    __syncthreads();
    s16x8 af[4], bfr[4];
    for (int m = 0; m < 4; ++m)
      af[m] = *(const s16x8*)(&At[(wr * 64 + m * 16 + l15) * 32 + l4 * 8]);
    for (int nn = 0; nn < 4; ++nn)
      bfr[nn] = *(const s16x8*)(&Bt[(wc * 64 + nn * 16 + l15) * 32 + l4 * 8]);
    for (int m = 0; m < 4; ++m)
      for (int nn = 0; nn < 4; ++nn)
        acc[m][nn] = __builtin_amdgcn_mfma_f32_16x16x32_bf16(af[m], bfr[nn], acc[m][nn], 0, 0, 0);
    __syncthreads();
  }

  for (int m = 0; m < 4; ++m) {
    int row0 = by * 128 + wr * 64 + m * 16 + l4 * 4;
    for (int nn = 0; nn < 4; ++nn) {
      int col = bx * 128 + wc * 64 + nn * 16 + l15;
      float bc = biasRow ? 0.f : bias[col];
      for (int r = 0; r < 4; ++r) {
        int row = row0 + r;
        float v = acc[m][nn][r] + (biasRow ? bias[row] : bc);
        C[(size_t)row * N + col] = (__bf16)v;
      }
    }
  }
}

// ---------- out-proj: out = gelu(X@Wm^T + bm), fp32; 64x128 tiles ---------
__global__ __launch_bounds__(256) void gemm_out(
    const __bf16* __restrict__ A, const float* __restrict__ Bw,
    const float* __restrict__ bias, float* __restrict__ C, int N)
{
  __shared__ __bf16 At[64 * 32];
  __shared__ __bf16 Bt[128 * 32];
  const int t = threadIdx.x;
  const int lane = t & 63, w = t >> 6;
  const int wr = w >> 1, wc = w & 1;
  const int l15 = lane & 15, l4 = lane >> 4;
  const int by = blockIdx.x, bx = blockIdx.y;

  f32x4 acc[2][4];
  for (int m = 0; m < 2; ++m)
    for (int nn = 0; nn < 4; ++nn) acc[m][nn] = (f32x4){0.f, 0.f, 0.f, 0.f};

  for (int kk = 0; kk < 256; kk += 32) {
    {
      int row = t >> 2, off0 = (t & 3) * 8;
      *(s16x8*)(&At[row * 32 + off0]) =
          *(const s16x8*)(A + (size_t)(by * 64 + row) * 256 + kk + off0);
    }
    for (int j = 0; j < 2; ++j) {
      int c = t + j * 256;
      int row = c >> 2, off0 = (c & 3) * 8;
      *(s16x8*)(&Bt[row * 32 + off0]) = cvt8(Bw + (size_t)(bx * 128 + row) * 256 + kk + off0);
    }
    __syncthreads();
    s16x8 af[2], bfr[4];
    for (int m = 0; m < 2; ++m)
      af[m] = *(const s16x8*)(&At[(wr * 32 + m * 16 + l15) * 32 + l4 * 8]);
    for (int nn = 0; nn < 4; ++nn)
      bfr[nn] = *(const s16x8*)(&Bt[(wc * 64 + nn * 16 + l15) * 32 + l4 * 8]);
    for (int m = 0; m < 2; ++m)
      for (int nn = 0; nn < 4; ++nn)
        acc[m][nn] = __builtin_amdgcn_mfma_f32_16x16x32_bf16(af[m], bfr[nn], acc[m][nn], 0, 0, 0);
    __syncthreads();
  }

  for (int m = 0; m < 2; ++m) {
    int row0 = by * 64 + wr * 32 + m * 16 + l4 * 4;
    for (int nn = 0; nn < 4; ++nn) {
      int col = bx * 128 + wc * 64 + nn * 16 + l15;
      float bc = bias[col];
      for (int r = 0; r < 4; ++r) {
        int row = row0 + r;
        C[(size_t)row * N + col] = fast_gelu(acc[m][nn][r] + bc);
      }
    }
  }
}

// ---------- attention (round-4 proven): X = softmax(QK^T/16)V -------------
#define KSTR 264
#define PSTR 136
__global__ __launch_bounds__(512, 2) void attn_kernel(
    const __bf16* __restrict__ Q, const __bf16* __restrict__ Km,
    const __bf16* __restrict__ Vt, __bf16* __restrict__ X,
    const int* __restrict__ offs, int total)
{
  __shared__ __bf16 smem[128 * KSTR];
  __bf16 (*Klds)[KSTR] = (__bf16(*)[KSTR])smem;
  __bf16 (*Plds)[PSTR] = (__bf16(*)[PSTR])smem;

  const int g = blockIdx.x;
  const int off = offs[g];
  const int n = offs[g + 1] - off;
  const int t = threadIdx.x, lane = t & 63, w = t >> 6;
  const int l15 = lane & 15, l4 = lane >> 4;
  const bool qact = (w * 16) < n;

  uint4 kst[8];
  #pragma unroll
  for (int j = 0; j < 8; ++j) {
    int row = j * 16 + (t >> 5);
    kst[j] = *(const uint4*)((const char*)(Km + (size_t)(off + row) * 256) + (t & 31) * 16);
  }
  s16x8 qf[8];
  if (qact) {
    int qr = w * 16 + l15; if (qr >= n) qr = n - 1;
    const __bf16* qp = Q + (size_t)(off + qr) * 256 + l4 * 8;
    #pragma unroll
    for (int kk = 0; kk < 8; ++kk) qf[kk] = *(const s16x8*)(qp + kk * 32);
  }
  #pragma unroll
  for (int j = 0; j < 8; ++j) {
    int row = j * 16 + (t >> 5);
    *(uint4*)((char*)&Klds[row][0] + (t & 31) * 16) = kst[j];
  }
  __syncthreads();

  f32x4 sacc[8];
  #pragma unroll
  for (int i = 0; i < 8; ++i) sacc[i] = (f32x4){0.f, 0.f, 0.f, 0.f};
  if (qact) {
    #pragma unroll
    for (int kt = 0; kt < 8; ++kt) {
      if (kt * 16 < n) {
        const __bf16* kp = &Klds[kt * 16 + l15][l4 * 8];
        #pragma unroll
        for (int kk = 0; kk < 8; ++kk) {
          s16x8 kf = *(const s16x8*)(kp + kk * 32);
          sacc[kt] = __builtin_amdgcn_mfma_f32_16x16x32_bf16(qf[kk], kf, sacc[kt], 0, 0, 0);
        }
      }
    }
  }
  __syncthreads();

  if (qact) {
    #pragma unroll
    for (int r = 0; r < 4; ++r) {
      float sv[8];
      float m = -1e30f;
      #pragma unroll
      for (int kt = 0; kt < 8; ++kt) {
        int key = kt * 16 + l15;
        float v = (key < n) ? sacc[kt][r] * 0.0625f : -1e30f;
        sv[kt] = v; m = fmaxf(m, v);
      }
      for (int o = 1; o < 16; o <<= 1) m = fmaxf(m, __shfl_xor(m, o));
      float p[8], sum = 0.f;
      #pragma unroll
      for (int kt = 0; kt < 8; ++kt) { p[kt] = __expf(sv[kt] - m); sum += p[kt]; }
      for (int o = 1; o < 16; o <<= 1) sum += __shfl_xor(sum, o);
      float inv = 1.f / sum;
      int q = w * 16 + l4 * 4 + r;
      #pragma unroll
      for (int kt = 0; kt < 8; ++kt)
        Plds[q][kt * 16 + l15] = (__bf16)(p[kt] * inv);
    }
  }
  __syncthreads();

  const int dbase = w * 32;
  f32x4 xacc[2][8];
  #pragma unroll
  for (int dt = 0; dt < 2; ++dt)
    #pragma unroll
    for (int qm = 0; qm < 8; ++qm) xacc[dt][qm] = (f32x4){0.f, 0.f, 0.f, 0.f};

  #pragma unroll
  for (int dt = 0; dt < 2; ++dt) {
    int d = dbase + dt * 16 + l15;
    s16x8 vf[4];
    #pragma unroll
    for (int ks = 0; ks < 4; ++ks) {
      int kc = off + ks * 32 + l4 * 8;
      if (kc > total - 8) kc = total - 8;
      vf[ks] = *(const s16x8*)(Vt + (size_t)d * total + kc);
    }
    #pragma unroll
    for (int qm = 0; qm < 8; ++qm) {
      #pragma unroll
      for (int ks = 0; ks < 4; ++ks) {
        if (ks * 32 < n) {
          s16x8 pa = *(const s16x8*)(&Plds[qm * 16 + l15][ks * 32 + l4 * 8]);
          xacc[dt][qm] = __builtin_amdgcn_mfma_f32_16x16x32_bf16(pa, vf[ks], xacc[dt][qm], 0, 0, 0);
        }
      }
    }
  }

  #pragma unroll
  for (int dt = 0; dt < 2; ++dt)
    #pragma unroll
    for (int qm = 0; qm < 8; ++qm)
      #pragma unroll
      for (int r = 0; r < 4; ++r) {
        int q = qm * 16 + l4 * 4 + r;
        if (q < n)
          X[(size_t)(off + q) * 256 + dbase + dt * 16 + l15] = (__bf16)xacc[dt][qm][r];
      }
}

// ---------------------------------------------------------------------------
extern "C" void kernel_launch(void* const* d_in, const int* in_sizes, int n_in,
                              void* d_out, int out_size, void* d_ws, size_t ws_size,
                              hipStream_t stream) {
  const float* rep2d = (const float*)d_in[0];
  const float* rep3d = (const float*)d_in[1];
  const int*   na    = (const int*)d_in[2];
  const float* wq23 = (const float*)d_in[3];  const float* bq23 = (const float*)d_in[4];
  const float* wk23 = (const float*)d_in[5];  const float* bk23 = (const float*)d_in[6];
  const float* wv23 = (const float*)d_in[7];  const float* bv23 = (const float*)d_in[8];
  const float* wq32 = (const float*)d_in[9];  const float* bq32 = (const float*)d_in[10];
  const float* wk32 = (const float*)d_in[11]; const float* bk32 = (const float*)d_in[12];
  const float* wv32 = (const float*)d_in[13]; const float* bv32 = (const float*)d_in[14];
  const float* wm23 = (const float*)d_in[15]; const float* bm23 = (const float*)d_in[16];
  const float* wm32 = (const float*)d_in[17]; const float* bm32 = (const float*)d_in[18];

  const int B = in_sizes[2];
  const int total = in_sizes[0] / 256;           // 40960
  float* out = (float*)d_out;

  char* ws = (char*)d_ws;
  const size_t SZ = (size_t)total * 256 * sizeof(__bf16);  // 20.97 MB
  const size_t need6 = 8192 + 6 * SZ;                      // 125.9 MB (fused)
  const size_t need3 = 8192 + 3 * SZ;                      // 62.9 MB (fallback)
  int* offs = (int*)ws;

  dim3 blk(256);
  dim3 gO(total / 64, 2);    // out-proj, 64-row tiles
  dim3 gA(B);                // attention: 1 block/graph
  dim3 blkA(512);

  if (ws_size >= need6) {
    __bf16* BQ1 = (__bf16*)(ws + 8192);
    __bf16* BK1 = (__bf16*)(ws + 8192 + SZ);
    __bf16* BV1 = (__bf16*)(ws + 8192 + 2 * SZ);
    __bf16* BQ2 = (__bf16*)(ws + 8192 + 3 * SZ);
    __bf16* BK2 = (__bf16*)(ws + 8192 + 4 * SZ);
    __bf16* BV2 = (__bf16*)(ws + 8192 + 5 * SZ);

    scan_kernel<<<1, 512, 0, stream>>>(na, offs, B, total, out);
    // rep2d feeds: Q23 (branch1 Q), K32+V32 (branch2 K/V)
    qkv_fused<<<total / 64, blk, 0, stream>>>(rep2d, wq23, bq23, wk32, bk32,
                                              wv32, bv32, BQ1, BK2, BV2, total);
    // rep3d feeds: Q32 (branch2 Q), K23+V23 (branch1 K/V)
    qkv_fused<<<total / 64, blk, 0, stream>>>(rep3d, wq32, bq32, wk23, bk23,
                                              wv23, bv23, BQ2, BK1, BV1, total);
    attn_kernel<<<gA, blkA, 0, stream>>>(BQ1, BK1, BV1, BQ1, offs, total);
    gemm_out<<<gO, blk, 0, stream>>>(BQ1, wm23, bm23, out, 256);
    attn_kernel<<<gA, blkA, 0, stream>>>(BQ2, BK2, BV2, BQ2, offs, total);
    gemm_out<<<gO, blk, 0, stream>>>(BQ2, wm32, bm32, out + (size_t)total * 256, 256);
  } else if (ws_size >= need3) {
    __bf16* BQ = (__bf16*)(ws + 8192);
    __bf16* BK = (__bf16*)(ws + 8192 + SZ);
    __bf16* BV = (__bf16*)(ws + 8192 + 2 * SZ);
    dim3 gP(total / 128, 2);
    dim3 gV(2, total / 128);

    scan_kernel<<<1, 512, 0, stream>>>(na, offs, B, total, out);
    gemm_kernel<<<gP, blk, 0, stream>>>(rep2d, wq23, bq23, BQ, 256, 0);
    gemm_kernel<<<gP, blk, 0, stream>>>(rep3d, wk23, bk23, BK, 256, 0);
    gemm_kernel<<<gV, blk, 0, stream>>>(wv23, rep3d, bv23, BV, total, 1);
    attn_kernel<<<gA, blkA, 0, stream>>>(BQ, BK, BV, BQ, offs, total);
    gemm_out<<<gO, blk, 0, stream>>>(BQ, wm23, bm23, out, 256);
    gemm_kernel<<<gP, blk, 0, stream>>>(rep3d, wq32, bq32, BQ, 256, 0);
    gemm_kernel<<<gP, blk, 0, stream>>>(rep2d, wk32, bk32, BK, 256, 0);
    gemm_kernel<<<gV, blk, 0, stream>>>(wv32, rep2d, bv32, BV, total, 1);
    attn_kernel<<<gA, blkA, 0, stream>>>(BQ, BK, BV, BQ, offs, total);
    gemm_out<<<gO, blk, 0, stream>>>(BQ, wm32, bm32, out + (size_t)total * 256, 256);
  } else {
    sentinel_kernel<<<1, 64, 0, stream>>>(out, 54321.0f);
  }
}